// Round 2
// 6530.105 us; speedup vs baseline: 1.1285x; 1.1285x over previous
//
#include <hip/hip_runtime.h>
#include <hip/hip_bf16.h>

// LSTM T=512, B=64, I=H=512, fp32 in/out, bf16 MFMA compute.
// Round 9 = Round 8 (wave specialization) + hang-hardening: every spin loop
// sleeps between probes (round 8's wave0 poll hot-spun 32 system-scope loads
// per iteration across 32 blocks -> plausible coherence-point starvation ->
// container-killing hang).
// Structure per block (512 thr = 8 waves):
//   waves 0-3 (recurrent, setprio 1): poll per-block flags (32 lanes of wave 0,
//     LDS-mirror relay to waves 1-3) -> 16 batched global_load_dwordx4 sc0 sc1
//     h loads + single vmcnt(0) drain -> 64 MFMA (W_hh frags streamed from L2,
//     no longer LDS) -> cell (+xg from LDS ring) -> publish h + per-block flag
//     (plain system store, no RMW contention).
//   waves 4-7 (x-producers): compute x_t*W_ih^T + bias up to 3 steps ahead into
//     a 3-slot LDS ring (48 KB), pairwise handoff (x-wave bt -> rec wave bt)
//     via LDS acquire/release flags. Backpressure via per-bt cons counters.
// Cross-block h exchange unchanged from proven round 7 (system-scope relaxed,
// MALL coherence point; no cache-maintenance ops -> W/x L2 stays warm).

typedef __attribute__((ext_vector_type(8))) short short8;
typedef __attribute__((ext_vector_type(4))) float f32x4;

#define T_STEPS 512
#define BATCH   64
#define HID     512
#define GATES   2048
#define BH      (BATCH * HID)   // 32768
#define NBLOCKS 32
#define WCHUNKS (4 * 16 * 64)   // frag chunks per block-slice
#define RING    3

__device__ __forceinline__ unsigned short f2bfu(float f) {
    union { __hip_bfloat16 h; unsigned short s; } u;
    u.h = __float2bfloat16(f);
    return u.s;
}
__device__ __forceinline__ float sigmoidf_fast(float x) {
    return 1.0f / (1.0f + __expf(-x));
}
__device__ __forceinline__ float tanhf_fast(float x) {
    return 2.0f / (1.0f + __expf(-2.0f * x)) - 1.0f;
}
// 16B system-scope (MALL-coherent, cache-bypassing) load; caller drains vmcnt.
__device__ __forceinline__ short8 sysload16(const unsigned short* p) {
    short8 r;
    asm volatile("global_load_dwordx4 %0, %1, off sc0 sc1"
                 : "=v"(r) : "v"(p) : "memory");
    return r;
}

// ---------------- prep: W fp32 -> bf16 fragment order; bias; h0; flags ----------------
// F[((jt*4+g)*16 + kb)*64 + lane][0..7] =
//   W[g*512 + jt*16 + (lane&15)][kb*32 + (lane>>4)*8 + j]
__global__ __launch_bounds__(256) void prep(
    const float* __restrict__ h0,
    const float* __restrict__ W_ih, const float* __restrict__ W_hh,
    const float* __restrict__ b_ih, const float* __restrict__ b_hh,
    unsigned short* __restrict__ WihF, unsigned short* __restrict__ WhhF,
    unsigned short* __restrict__ hbuf0, float* __restrict__ bias,
    int* __restrict__ hflag)
{
    const int tid = blockIdx.x * 256 + threadIdx.x;   // grid covers [0, 262144)
    {
        const int which = (tid >= 131072);
        const int t2   = tid & 131071;
        const int lane = t2 & 63;
        const int kb   = (t2 >> 6) & 15;
        const int g    = (t2 >> 10) & 3;
        const int jt   = t2 >> 12;            // 0..31
        const float* W = which ? W_hh : W_ih;
        unsigned short* F = which ? WhhF : WihF;
        const int row = g * HID + jt * 16 + (lane & 15);
        const int k   = kb * 32 + (lane >> 4) * 8;
        const float* src = W + (size_t)row * HID + k;
        unsigned short* dst = F + ((((size_t)jt * 4 + g) * 16 + kb) * 64 + lane) * 8;
#pragma unroll
        for (int j = 0; j < 8; ++j) dst[j] = f2bfu(src[j]);
    }
    if (tid < GATES)   bias[tid]  = b_ih[tid] + b_hh[tid];
    if (tid < BH)      hbuf0[tid] = f2bfu(h0[tid]);
    if (tid < T_STEPS * NBLOCKS) hflag[tid] = 0;
}

// ---------------- persistent scan kernel ----------------
__global__ __launch_bounds__(512, 2) void lstm_persistent(
    const float* __restrict__ input,     // [512,64,512] fp32
    const float* __restrict__ c0,        // [64,512] fp32
    const unsigned short* __restrict__ WihF,
    const unsigned short* __restrict__ WhhF,
    const float* __restrict__ bias,
    unsigned short* __restrict__ hbuf,   // [2][BH] bf16
    int* __restrict__ hflag,             // [T_STEPS][NBLOCKS]
    float* __restrict__ out)             // [T*BH | BH | BH] fp32
{
    __shared__ f32x4 ring[RING][4][256];   // [slot][gate][bt*64+lane] = 48 KB
    __shared__ int xg_ready[RING][4];      // step+1 when slot/bt produced
    __shared__ int cons[4];                // recurrent progress per bt
    __shared__ int arr2[2];                // publish-barrier arrivals (ping-pong)
    __shared__ int mirror;                 // wave0's relay of global flag state

    const int tid  = threadIdx.x;
    const int lane = tid & 63;
    const int w    = tid >> 6;      // 0..7
    const int bt   = w & 3;         // batch tile
    const int jt   = blockIdx.x;    // j-tile 0..31
    const int quad = lane >> 4;
    const int lr   = lane & 15;

    if (tid < RING * 4)              (&xg_ready[0][0])[tid] = 0;
    else if (tid < RING * 4 + 4)     cons[tid - RING * 4] = 0;
    else if (tid < RING * 4 + 6)     arr2[tid - RING * 4 - 4] = 0;
    else if (tid == RING * 4 + 6)    mirror = 0;
    __syncthreads();   // single full-block barrier, before role divergence

    const int brow  = bt * 16 + lr;           // batch row of this lane's cells
    const int jbase = jt * 16 + quad * 4;     // first of 4 consecutive j columns

    if (w >= 4) {
        // ---------------- x-producer wave (paired with rec wave bt) ----------------
        float bs[4][4];
#pragma unroll
        for (int g = 0; g < 4; ++g)
#pragma unroll
            for (int r = 0; r < 4; ++r)
                bs[g][r] = bias[g * HID + jbase + r];
        const unsigned short* wih_lane =
            WihF + (size_t)jt * WCHUNKS * 8 + (size_t)lane * 8;

        for (int t = 0; t < T_STEPS; ++t) {
            const int s = t % RING;
            if (t >= RING) {   // slot free once paired consumer did step t-RING
                while (__hip_atomic_load(&cons[bt], __ATOMIC_ACQUIRE,
                                         __HIP_MEMORY_SCOPE_WORKGROUP) < t - (RING - 1))
                    __builtin_amdgcn_s_sleep(2);
            }
            f32x4 acc[4];
#pragma unroll
            for (int g = 0; g < 4; ++g)
                acc[g] = (f32x4){bs[g][0], bs[g][1], bs[g][2], bs[g][3]};
            const float* xp = input + ((size_t)t * BATCH + brow) * HID + quad * 8;
#pragma unroll
            for (int kb = 0; kb < 16; ++kb) {
                const f32x4 f0 = *reinterpret_cast<const f32x4*>(xp + kb * 32);
                const f32x4 f1 = *reinterpret_cast<const f32x4*>(xp + kb * 32 + 4);
                union { __hip_bfloat162 b2[4]; short8 s8; } bu;
                bu.b2[0] = __float22bfloat162_rn(make_float2(f0.x, f0.y));
                bu.b2[1] = __float22bfloat162_rn(make_float2(f0.z, f0.w));
                bu.b2[2] = __float22bfloat162_rn(make_float2(f1.x, f1.y));
                bu.b2[3] = __float22bfloat162_rn(make_float2(f1.z, f1.w));
#pragma unroll
                for (int g = 0; g < 4; ++g) {
                    short8 afrag = *reinterpret_cast<const short8*>(
                        wih_lane + ((size_t)(g * 16 + kb) * 64) * 8);
                    acc[g] = __builtin_amdgcn_mfma_f32_16x16x32_bf16(
                        afrag, bu.s8, acc[g], 0, 0, 0);
                }
            }
#pragma unroll
            for (int g = 0; g < 4; ++g)
                ring[s][g][bt * 64 + lane] = acc[g];     // ds_write_b128
            // release: drains lgkm before flag; consumer acquire pairs with it
            __hip_atomic_store(&xg_ready[s][bt], t + 1, __ATOMIC_RELEASE,
                               __HIP_MEMORY_SCOPE_WORKGROUP);
        }
        return;
    }

    // ---------------- recurrent wave ----------------
    __builtin_amdgcn_s_setprio(1);   // favor the critical-path waves

    f32x4 c = *reinterpret_cast<const f32x4*>(c0 + (size_t)brow * HID + jbase);
    const unsigned short* whh_lane =
        WhhF + (size_t)jt * WCHUNKS * 8 + (size_t)lane * 8;
    float hlast[4];

    for (int t = 0; t < T_STEPS; ++t) {
        const int s = t % RING;

        // xg from paired producer (normally already ready)
        while (__hip_atomic_load(&xg_ready[s][bt], __ATOMIC_ACQUIRE,
                                 __HIP_MEMORY_SCOPE_WORKGROUP) < t + 1)
            __builtin_amdgcn_s_sleep(1);
        f32x4 xg[4];
#pragma unroll
        for (int g = 0; g < 4; ++g) xg[g] = ring[s][g][bt * 64 + lane];

        // wait for h_t: wave0 polls the 32 per-block flags, relays via LDS.
        // s_sleep between probes — hot-spinning system-scope loads from 32
        // blocks at once risks starving the coherence point (round-8 hang).
        if (t > 0) {
            if (w == 0) {
                int* hf = hflag + (size_t)(t - 1) * NBLOCKS;
                for (;;) {
                    int f = (lane < NBLOCKS)
                        ? __hip_atomic_load(&hf[lane], __ATOMIC_RELAXED,
                                            __HIP_MEMORY_SCOPE_SYSTEM)
                        : 1;
                    if (__all(f != 0)) break;
                    __builtin_amdgcn_s_sleep(1);
                }
                __hip_atomic_store(&mirror, t, __ATOMIC_RELEASE,
                                   __HIP_MEMORY_SCOPE_WORKGROUP);
            } else {
                while (__hip_atomic_load(&mirror, __ATOMIC_ACQUIRE,
                                         __HIP_MEMORY_SCOPE_WORKGROUP) < t)
                    __builtin_amdgcn_s_sleep(1);
            }
            __atomic_signal_fence(__ATOMIC_ACQ_REL);   // no h-load hoist past poll
            __builtin_amdgcn_sched_barrier(0);
        }

        // batched h loads: 16 x dwordx4 sc0 sc1, single drain (rule-18 pattern)
        const unsigned short* hp =
            hbuf + (size_t)(t & 1) * BH + (size_t)brow * HID + quad * 8;
        short8 hreg[16];
#pragma unroll
        for (int kb = 0; kb < 16; ++kb) hreg[kb] = sysload16(hp + kb * 32);
        asm volatile("s_waitcnt vmcnt(0)" ::: "memory");
        __builtin_amdgcn_sched_barrier(0);

        // h-side MFMA; W_hh frags stream from L2 (64 KB/block, stays hot)
        f32x4 acc[4];
#pragma unroll
        for (int g = 0; g < 4; ++g) acc[g] = (f32x4){0.f, 0.f, 0.f, 0.f};
#pragma unroll
        for (int kb = 0; kb < 16; ++kb) {
#pragma unroll
            for (int g = 0; g < 4; ++g) {
                short8 afrag = *reinterpret_cast<const short8*>(
                    whh_lane + ((size_t)(g * 16 + kb) * 64) * 8);
                acc[g] = __builtin_amdgcn_mfma_f32_16x16x32_bf16(
                    afrag, hreg[kb], acc[g], 0, 0, 0);
            }
        }

        // LSTM cell (xg already contains bias + x-projection)
        unsigned long long hpack = 0;
        f32x4 outv;
#pragma unroll
        for (int r = 0; r < 4; ++r) {
            const float i_ = sigmoidf_fast(acc[0][r] + xg[0][r]);
            const float f_ = sigmoidf_fast(acc[1][r] + xg[1][r]);
            const float g_ = tanhf_fast(acc[2][r] + xg[2][r]);
            const float o_ = sigmoidf_fast(acc[3][r] + xg[3][r]);
            const float cr = f_ * c[r] + i_ * g_;
            c[r] = cr;
            const float h = o_ * tanhf_fast(cr);
            hlast[r] = h;
            outv[r] = h;
            hpack |= (unsigned long long)f2bfu(h) << (16 * r);
        }

        // publish h_{t+1} (system write-through) -> drain -> release ring slot
        __hip_atomic_store(reinterpret_cast<unsigned long long*>(
                               hbuf + (size_t)((t + 1) & 1) * BH +
                               (size_t)brow * HID + jbase),
                           hpack, __ATOMIC_RELAXED, __HIP_MEMORY_SCOPE_SYSTEM);
        __threadfence_block();   // s_waitcnt vmcnt(0) lgkmcnt(0); no cache ops
        __hip_atomic_store(&cons[bt], t + 1, __ATOMIC_RELEASE,
                           __HIP_MEMORY_SCOPE_WORKGROUP);
        // intra-block publish barrier: last-arriving wave sets this block's flag
        if (lane == 0) {
            int old = atomicAdd(&arr2[t & 1], 1);
            if (old == 3) {
                arr2[t & 1] = 0;
                __hip_atomic_store(&hflag[(size_t)t * NBLOCKS + jt], 1,
                                   __ATOMIC_RELAXED, __HIP_MEMORY_SCOPE_SYSTEM);
            }
        }

        // out store (off critical path, nontemporal)
        __builtin_nontemporal_store(
            outv, reinterpret_cast<f32x4*>(
                      out + ((size_t)t * BATCH + brow) * HID + jbase));
    }

    // tails: hT, cT from registers
    float* hT = out + (size_t)T_STEPS * BH;
    float* cT = hT + BH;
    f32x4 hv4;
#pragma unroll
    for (int r = 0; r < 4; ++r) hv4[r] = hlast[r];
    *reinterpret_cast<f32x4*>(hT + (size_t)brow * HID + jbase) = hv4;
    *reinterpret_cast<f32x4*>(cT + (size_t)brow * HID + jbase) = c;
}

extern "C" void kernel_launch(void* const* d_in, const int* in_sizes, int n_in,
                              void* d_out, int out_size, void* d_ws, size_t ws_size,
                              hipStream_t stream) {
    const float* input = (const float*)d_in[0];
    const float* h0    = (const float*)d_in[1];
    const float* c0    = (const float*)d_in[2];
    const float* W_ih  = (const float*)d_in[3];
    const float* W_hh  = (const float*)d_in[4];
    const float* b_ih  = (const float*)d_in[5];
    const float* b_hh  = (const float*)d_in[6];
    float* out = (float*)d_out;

    // ws layout (~4.5 MB): WihF | WhhF (bf16 frags, 2 MB each) | hbuf[2] bf16 |
    //                      bias fp32 | hflag int[512*32]
    char* ws = (char*)d_ws;
    unsigned short* WihF = (unsigned short*)ws;
    unsigned short* WhhF = WihF + (size_t)GATES * HID;
    unsigned short* hbuf = WhhF + (size_t)GATES * HID;
    float* bias = (float*)(hbuf + 2 * BH);
    int* hflag = (int*)(bias + GATES);

    prep<<<1024, 256, 0, stream>>>(h0, W_ih, W_hh, b_ih, b_hh,
                                   WihF, WhhF, hbuf, bias, hflag);

    lstm_persistent<<<NBLOCKS, 512, 0, stream>>>(
        input, c0, WihF, WhhF, bias, hbuf, hflag, out);
}

// Round 3
// 5725.263 us; speedup vs baseline: 1.2871x; 1.1406x over previous
//
#include <hip/hip_runtime.h>
#include <hip/hip_bf16.h>

// LSTM T=512, B=64, I=H=512, fp32 in/out, bf16 MFMA compute.
// Round 10 = Round 9 (wave specialization, proven) + post-arrival path repair:
//  - W_hh fragments back in LDS (round 9 streamed them from L2: ~256 KB/step/CU
//    serially AFTER h arrived + latency jitter feeding the 32-block straggler
//    wait). LDS now: W_hh 64 KB + ring 48 KB = ~115 KB.
//  - gates 0-1 of W_hh reg-cached per rec wave (64 VGPRs, loaded once) ->
//    halves per-step LDS read volume on the critical path. Producers reg-cache
//    gates 0-1 of W_ih to halve their per-step L2 pull (fabric contention).
//  - tail reorder: cell -> issue h/out stores -> drain -> flag ASAP; the next
//    step's xg wait/read + cons release moved into the post-flag shadow
//    (software-pipelined xg_next), off the inter-block critical path.
// Sync protocol (per-block flags, wave0 poll + LDS mirror, sleepy spins,
// system-scope relaxed h exchange through MALL) unchanged from round 9.

typedef __attribute__((ext_vector_type(8))) short short8;
typedef __attribute__((ext_vector_type(4))) float f32x4;

#define T_STEPS 512
#define BATCH   64
#define HID     512
#define GATES   2048
#define BH      (BATCH * HID)   // 32768
#define NBLOCKS 32
#define WCHUNKS (4 * 16 * 64)   // frag chunks per block-slice
#define RING    3

__device__ __forceinline__ unsigned short f2bfu(float f) {
    union { __hip_bfloat16 h; unsigned short s; } u;
    u.h = __float2bfloat16(f);
    return u.s;
}
__device__ __forceinline__ float sigmoidf_fast(float x) {
    return 1.0f / (1.0f + __expf(-x));
}
__device__ __forceinline__ float tanhf_fast(float x) {
    return 2.0f / (1.0f + __expf(-2.0f * x)) - 1.0f;
}
// 16B system-scope (MALL-coherent, cache-bypassing) load; caller drains vmcnt.
__device__ __forceinline__ short8 sysload16(const unsigned short* p) {
    short8 r;
    asm volatile("global_load_dwordx4 %0, %1, off sc0 sc1"
                 : "=v"(r) : "v"(p) : "memory");
    return r;
}

// ---------------- prep: W fp32 -> bf16 fragment order; bias; h0; flags ----------------
// F[((jt*4+g)*16 + kb)*64 + lane][0..7] =
//   W[g*512 + jt*16 + (lane&15)][kb*32 + (lane>>4)*8 + j]
__global__ __launch_bounds__(256) void prep(
    const float* __restrict__ h0,
    const float* __restrict__ W_ih, const float* __restrict__ W_hh,
    const float* __restrict__ b_ih, const float* __restrict__ b_hh,
    unsigned short* __restrict__ WihF, unsigned short* __restrict__ WhhF,
    unsigned short* __restrict__ hbuf0, float* __restrict__ bias,
    int* __restrict__ hflag)
{
    const int tid = blockIdx.x * 256 + threadIdx.x;   // grid covers [0, 262144)
    {
        const int which = (tid >= 131072);
        const int t2   = tid & 131071;
        const int lane = t2 & 63;
        const int kb   = (t2 >> 6) & 15;
        const int g    = (t2 >> 10) & 3;
        const int jt   = t2 >> 12;            // 0..31
        const float* W = which ? W_hh : W_ih;
        unsigned short* F = which ? WhhF : WihF;
        const int row = g * HID + jt * 16 + (lane & 15);
        const int k   = kb * 32 + (lane >> 4) * 8;
        const float* src = W + (size_t)row * HID + k;
        unsigned short* dst = F + ((((size_t)jt * 4 + g) * 16 + kb) * 64 + lane) * 8;
#pragma unroll
        for (int j = 0; j < 8; ++j) dst[j] = f2bfu(src[j]);
    }
    if (tid < GATES)   bias[tid]  = b_ih[tid] + b_hh[tid];
    if (tid < BH)      hbuf0[tid] = f2bfu(h0[tid]);
    if (tid < T_STEPS * NBLOCKS) hflag[tid] = 0;
}

// ---------------- persistent scan kernel ----------------
__global__ __launch_bounds__(512, 2) void lstm_persistent(
    const float* __restrict__ input,     // [512,64,512] fp32
    const float* __restrict__ c0,        // [64,512] fp32
    const unsigned short* __restrict__ WihF,
    const unsigned short* __restrict__ WhhF,
    const float* __restrict__ bias,
    unsigned short* __restrict__ hbuf,   // [2][BH] bf16
    int* __restrict__ hflag,             // [T_STEPS][NBLOCKS]
    float* __restrict__ out)             // [T*BH | BH | BH] fp32
{
    __shared__ unsigned short WhhL[WCHUNKS * 8];   // 64 KB, whole t-loop
    __shared__ f32x4 ring[RING][4][256];   // [slot][gate][bt*64+lane] = 48 KB
    __shared__ int xg_ready[RING][4];      // step+1 when slot/bt produced
    __shared__ int cons[4];                // xg consumed up to (step+1) per bt
    __shared__ int arr2[2];                // publish-barrier arrivals (ping-pong)
    __shared__ int mirror;                 // wave0's relay of global flag state

    const int tid  = threadIdx.x;
    const int lane = tid & 63;
    const int w    = tid >> 6;      // 0..7
    const int bt   = w & 3;         // batch tile
    const int jt   = blockIdx.x;    // j-tile 0..31
    const int quad = lane >> 4;
    const int lr   = lane & 15;

    if (tid < RING * 4)              (&xg_ready[0][0])[tid] = 0;
    else if (tid < RING * 4 + 4)     cons[tid - RING * 4] = 0;
    else if (tid < RING * 4 + 6)     arr2[tid - RING * 4 - 4] = 0;
    else if (tid == RING * 4 + 6)    mirror = 0;

    // cooperative stage: this block's W_hh fragment slice -> LDS (all 8 waves)
    {
        const short8* src = reinterpret_cast<const short8*>(
            WhhF + (size_t)jt * WCHUNKS * 8);
        short8* dst = reinterpret_cast<short8*>(WhhL);
        for (int idx = tid; idx < WCHUNKS; idx += 512) dst[idx] = src[idx];
    }
    __syncthreads();   // LDS staged + sync vars init, before role divergence

    const int brow  = bt * 16 + lr;           // batch row of this lane's cells
    const int jbase = jt * 16 + quad * 4;     // first of 4 consecutive j columns

    if (w >= 4) {
        // ---------------- x-producer wave (paired with rec wave bt) ----------------
        float bs[4][4];
#pragma unroll
        for (int g = 0; g < 4; ++g)
#pragma unroll
            for (int r = 0; r < 4; ++r)
                bs[g][r] = bias[g * HID + jbase + r];
        const unsigned short* wih_lane =
            WihF + (size_t)jt * WCHUNKS * 8 + (size_t)lane * 8;

        // reg-cache gates 0-1 of W_ih (loop-invariant; halves per-step L2 pull)
        short8 wih_reg[2][16];
#pragma unroll
        for (int g = 0; g < 2; ++g)
#pragma unroll
            for (int kb = 0; kb < 16; ++kb)
                wih_reg[g][kb] = *reinterpret_cast<const short8*>(
                    wih_lane + ((size_t)(g * 16 + kb) * 64) * 8);

        for (int t = 0; t < T_STEPS; ++t) {
            const int s = t % RING;
            if (t >= RING) {   // slot free once paired consumer read xg[t-RING]
                while (__hip_atomic_load(&cons[bt], __ATOMIC_ACQUIRE,
                                         __HIP_MEMORY_SCOPE_WORKGROUP) < t - (RING - 1))
                    __builtin_amdgcn_s_sleep(2);
            }
            f32x4 acc[4];
#pragma unroll
            for (int g = 0; g < 4; ++g)
                acc[g] = (f32x4){bs[g][0], bs[g][1], bs[g][2], bs[g][3]};
            const float* xp = input + ((size_t)t * BATCH + brow) * HID + quad * 8;
#pragma unroll
            for (int kb = 0; kb < 16; ++kb) {
                const f32x4 f0 = *reinterpret_cast<const f32x4*>(xp + kb * 32);
                const f32x4 f1 = *reinterpret_cast<const f32x4*>(xp + kb * 32 + 4);
                union { __hip_bfloat162 b2[4]; short8 s8; } bu;
                bu.b2[0] = __float22bfloat162_rn(make_float2(f0.x, f0.y));
                bu.b2[1] = __float22bfloat162_rn(make_float2(f0.z, f0.w));
                bu.b2[2] = __float22bfloat162_rn(make_float2(f1.x, f1.y));
                bu.b2[3] = __float22bfloat162_rn(make_float2(f1.z, f1.w));
#pragma unroll
                for (int g = 0; g < 2; ++g)
                    acc[g] = __builtin_amdgcn_mfma_f32_16x16x32_bf16(
                        wih_reg[g][kb], bu.s8, acc[g], 0, 0, 0);
#pragma unroll
                for (int g = 2; g < 4; ++g) {
                    short8 afrag = *reinterpret_cast<const short8*>(
                        wih_lane + ((size_t)(g * 16 + kb) * 64) * 8);
                    acc[g] = __builtin_amdgcn_mfma_f32_16x16x32_bf16(
                        afrag, bu.s8, acc[g], 0, 0, 0);
                }
            }
#pragma unroll
            for (int g = 0; g < 4; ++g)
                ring[s][g][bt * 64 + lane] = acc[g];     // ds_write_b128
            // release: drains lgkm before flag; consumer acquire pairs with it
            __hip_atomic_store(&xg_ready[s][bt], t + 1, __ATOMIC_RELEASE,
                               __HIP_MEMORY_SCOPE_WORKGROUP);
        }
        return;
    }

    // ---------------- recurrent wave ----------------
    __builtin_amdgcn_s_setprio(1);   // favor the critical-path waves

    f32x4 c = *reinterpret_cast<const f32x4*>(c0 + (size_t)brow * HID + jbase);
    float hlast[4];

    // reg-cache gates 0-1 of W_hh from LDS (loop-invariant, 64 VGPRs)
    short8 whh_reg[2][16];
#pragma unroll
    for (int g = 0; g < 2; ++g)
#pragma unroll
        for (int kb = 0; kb < 16; ++kb)
            whh_reg[g][kb] =
                reinterpret_cast<const short8*>(WhhL)[(g * 16 + kb) * 64 + lane];

    // prologue: xg for step 0
    f32x4 xg[4];
    {
        while (__hip_atomic_load(&xg_ready[0][bt], __ATOMIC_ACQUIRE,
                                 __HIP_MEMORY_SCOPE_WORKGROUP) < 1)
            __builtin_amdgcn_s_sleep(1);
#pragma unroll
        for (int g = 0; g < 4; ++g) xg[g] = ring[0][g][bt * 64 + lane];
        __hip_atomic_store(&cons[bt], 1, __ATOMIC_RELEASE,
                           __HIP_MEMORY_SCOPE_WORKGROUP);
    }

    for (int t = 0; t < T_STEPS; ++t) {
        // wait for h_t: wave0 polls the 32 per-block flags, relays via LDS
        if (t > 0) {
            if (w == 0) {
                int* hf = hflag + (size_t)(t - 1) * NBLOCKS;
                for (;;) {
                    int f = (lane < NBLOCKS)
                        ? __hip_atomic_load(&hf[lane], __ATOMIC_RELAXED,
                                            __HIP_MEMORY_SCOPE_SYSTEM)
                        : 1;
                    if (__all(f != 0)) break;
                    __builtin_amdgcn_s_sleep(1);
                }
                __hip_atomic_store(&mirror, t, __ATOMIC_RELEASE,
                                   __HIP_MEMORY_SCOPE_WORKGROUP);
            } else {
                while (__hip_atomic_load(&mirror, __ATOMIC_ACQUIRE,
                                         __HIP_MEMORY_SCOPE_WORKGROUP) < t)
                    __builtin_amdgcn_s_sleep(1);
            }
            __atomic_signal_fence(__ATOMIC_ACQ_REL);   // no h-load hoist past poll
            __builtin_amdgcn_sched_barrier(0);
        }

        // batched h loads: 16 x dwordx4 sc0 sc1, single drain (rule-18 pattern)
        const unsigned short* hp =
            hbuf + (size_t)(t & 1) * BH + (size_t)brow * HID + quad * 8;
        short8 hreg[16];
#pragma unroll
        for (int kb = 0; kb < 16; ++kb) hreg[kb] = sysload16(hp + kb * 32);
        asm volatile("s_waitcnt vmcnt(0)" ::: "memory");
        __builtin_amdgcn_sched_barrier(0);

        // h-side MFMA: gates 0-1 from registers, gates 2-3 from LDS
        f32x4 acc[4];
#pragma unroll
        for (int g = 0; g < 4; ++g) acc[g] = (f32x4){0.f, 0.f, 0.f, 0.f};
#pragma unroll
        for (int kb = 0; kb < 16; ++kb) {
#pragma unroll
            for (int g = 0; g < 2; ++g)
                acc[g] = __builtin_amdgcn_mfma_f32_16x16x32_bf16(
                    whh_reg[g][kb], hreg[kb], acc[g], 0, 0, 0);
#pragma unroll
            for (int g = 2; g < 4; ++g) {
                short8 afrag =
                    reinterpret_cast<const short8*>(WhhL)[(g * 16 + kb) * 64 + lane];
                acc[g] = __builtin_amdgcn_mfma_f32_16x16x32_bf16(
                    afrag, hreg[kb], acc[g], 0, 0, 0);
            }
        }

        // LSTM cell (xg already contains bias + x-projection)
        unsigned long long hpack = 0;
        f32x4 outv;
#pragma unroll
        for (int r = 0; r < 4; ++r) {
            const float i_ = sigmoidf_fast(acc[0][r] + xg[0][r]);
            const float f_ = sigmoidf_fast(acc[1][r] + xg[1][r]);
            const float g_ = tanhf_fast(acc[2][r] + xg[2][r]);
            const float o_ = sigmoidf_fast(acc[3][r] + xg[3][r]);
            const float cr = f_ * c[r] + i_ * g_;
            c[r] = cr;
            const float h = o_ * tanhf_fast(cr);
            hlast[r] = h;
            outv[r] = h;
            hpack |= (unsigned long long)f2bfu(h) << (16 * r);
        }

        // publish h_{t+1} + out, drain once, flag ASAP (inter-block critical path)
        __hip_atomic_store(reinterpret_cast<unsigned long long*>(
                               hbuf + (size_t)((t + 1) & 1) * BH +
                               (size_t)brow * HID + jbase),
                           hpack, __ATOMIC_RELAXED, __HIP_MEMORY_SCOPE_SYSTEM);
        __builtin_nontemporal_store(
            outv, reinterpret_cast<f32x4*>(
                      out + ((size_t)t * BATCH + brow) * HID + jbase));
        __threadfence_block();   // s_waitcnt vmcnt(0) lgkmcnt(0); no cache ops
        if (lane == 0) {
            int old = atomicAdd(&arr2[t & 1], 1);
            if (old == 3) {
                arr2[t & 1] = 0;
                __hip_atomic_store(&hflag[(size_t)t * NBLOCKS + jt], 1,
                                   __ATOMIC_RELAXED, __HIP_MEMORY_SCOPE_SYSTEM);
            }
        }

        // post-flag shadow: pull next step's xg from the LDS ring
        if (t + 1 < T_STEPS) {
            const int sn = (t + 1) % RING;
            while (__hip_atomic_load(&xg_ready[sn][bt], __ATOMIC_ACQUIRE,
                                     __HIP_MEMORY_SCOPE_WORKGROUP) < t + 2)
                __builtin_amdgcn_s_sleep(1);
#pragma unroll
            for (int g = 0; g < 4; ++g) xg[g] = ring[sn][g][bt * 64 + lane];
            __hip_atomic_store(&cons[bt], t + 2, __ATOMIC_RELEASE,
                               __HIP_MEMORY_SCOPE_WORKGROUP);
        }
    }

    // tails: hT, cT from registers
    float* hT = out + (size_t)T_STEPS * BH;
    float* cT = hT + BH;
    f32x4 hv4;
#pragma unroll
    for (int r = 0; r < 4; ++r) hv4[r] = hlast[r];
    *reinterpret_cast<f32x4*>(hT + (size_t)brow * HID + jbase) = hv4;
    *reinterpret_cast<f32x4*>(cT + (size_t)brow * HID + jbase) = c;
}

extern "C" void kernel_launch(void* const* d_in, const int* in_sizes, int n_in,
                              void* d_out, int out_size, void* d_ws, size_t ws_size,
                              hipStream_t stream) {
    const float* input = (const float*)d_in[0];
    const float* h0    = (const float*)d_in[1];
    const float* c0    = (const float*)d_in[2];
    const float* W_ih  = (const float*)d_in[3];
    const float* W_hh  = (const float*)d_in[4];
    const float* b_ih  = (const float*)d_in[5];
    const float* b_hh  = (const float*)d_in[6];
    float* out = (float*)d_out;

    // ws layout (~4.5 MB): WihF | WhhF (bf16 frags, 2 MB each) | hbuf[2] bf16 |
    //                      bias fp32 | hflag int[512*32]
    char* ws = (char*)d_ws;
    unsigned short* WihF = (unsigned short*)ws;
    unsigned short* WhhF = WihF + (size_t)GATES * HID;
    unsigned short* hbuf = WhhF + (size_t)GATES * HID;
    float* bias = (float*)(hbuf + 2 * BH);
    int* hflag = (int*)(bias + GATES);

    prep<<<1024, 256, 0, stream>>>(h0, W_ih, W_hh, b_ih, b_hh,
                                   WihF, WhhF, hbuf, bias, hflag);

    lstm_persistent<<<NBLOCKS, 512, 0, stream>>>(
        input, c0, WihF, WhhF, bias, hbuf, hflag, out);
}

// Round 4
// 5647.601 us; speedup vs baseline: 1.3048x; 1.0138x over previous
//
#include <hip/hip_runtime.h>
#include <hip/hip_bf16.h>

// LSTM T=512, B=64, I=H=512, fp32 in/out, bf16 MFMA compute.
// Round 11 = Round 10 with exactly two changes (A/B on coherence scope):
//  1. All cross-block exchange ops (h stores, h loads via sc0 sc1 asm, flag
//     store, flag poll) switch SYSTEM -> AGENT scope. Agent = device-wide,
//     cross-XCD coherent (sufficient: host never touches these buffers
//     mid-kernel). Hypothesis: system scope orders against the host-visible
//     coherence point (far); agent stops at the MALL -> much shorter RT.
//     Round 6's slowness was agent *fences* (L2 wb/inv); agent *atomics*
//     carry no cache-maintenance.
//  2. The nontemporal out-store moves AFTER flag publication (round 10 had it
//     before the vmcnt(0) drain, putting an HBM write-ack on the inter-block
//     critical path every step).
// Everything else byte-identical to round 10: 8 waves (4 rec + 4 x-producer),
// W_hh in LDS + gates 0-1 reg-cached, 3-slot xg LDS ring, per-block flags,
// wave0 32-lane poll + LDS mirror, sleepy spins.

typedef __attribute__((ext_vector_type(8))) short short8;
typedef __attribute__((ext_vector_type(4))) float f32x4;

#define T_STEPS 512
#define BATCH   64
#define HID     512
#define GATES   2048
#define BH      (BATCH * HID)   // 32768
#define NBLOCKS 32
#define WCHUNKS (4 * 16 * 64)   // frag chunks per block-slice
#define RING    3

__device__ __forceinline__ unsigned short f2bfu(float f) {
    union { __hip_bfloat16 h; unsigned short s; } u;
    u.h = __float2bfloat16(f);
    return u.s;
}
__device__ __forceinline__ float sigmoidf_fast(float x) {
    return 1.0f / (1.0f + __expf(-x));
}
__device__ __forceinline__ float tanhf_fast(float x) {
    return 2.0f / (1.0f + __expf(-2.0f * x)) - 1.0f;
}
// 16B cache-bypassing load (L1+L2 skipped, reads the MALL coherence point);
// caller drains vmcnt. Correct consumer side for agent-scope publishes.
__device__ __forceinline__ short8 sysload16(const unsigned short* p) {
    short8 r;
    asm volatile("global_load_dwordx4 %0, %1, off sc0 sc1"
                 : "=v"(r) : "v"(p) : "memory");
    return r;
}

// ---------------- prep: W fp32 -> bf16 fragment order; bias; h0; flags ----------------
// F[((jt*4+g)*16 + kb)*64 + lane][0..7] =
//   W[g*512 + jt*16 + (lane&15)][kb*32 + (lane>>4)*8 + j]
__global__ __launch_bounds__(256) void prep(
    const float* __restrict__ h0,
    const float* __restrict__ W_ih, const float* __restrict__ W_hh,
    const float* __restrict__ b_ih, const float* __restrict__ b_hh,
    unsigned short* __restrict__ WihF, unsigned short* __restrict__ WhhF,
    unsigned short* __restrict__ hbuf0, float* __restrict__ bias,
    int* __restrict__ hflag)
{
    const int tid = blockIdx.x * 256 + threadIdx.x;   // grid covers [0, 262144)
    {
        const int which = (tid >= 131072);
        const int t2   = tid & 131071;
        const int lane = t2 & 63;
        const int kb   = (t2 >> 6) & 15;
        const int g    = (t2 >> 10) & 3;
        const int jt   = t2 >> 12;            // 0..31
        const float* W = which ? W_hh : W_ih;
        unsigned short* F = which ? WhhF : WihF;
        const int row = g * HID + jt * 16 + (lane & 15);
        const int k   = kb * 32 + (lane >> 4) * 8;
        const float* src = W + (size_t)row * HID + k;
        unsigned short* dst = F + ((((size_t)jt * 4 + g) * 16 + kb) * 64 + lane) * 8;
#pragma unroll
        for (int j = 0; j < 8; ++j) dst[j] = f2bfu(src[j]);
    }
    if (tid < GATES)   bias[tid]  = b_ih[tid] + b_hh[tid];
    if (tid < BH)      hbuf0[tid] = f2bfu(h0[tid]);
    if (tid < T_STEPS * NBLOCKS) hflag[tid] = 0;
}

// ---------------- persistent scan kernel ----------------
__global__ __launch_bounds__(512, 2) void lstm_persistent(
    const float* __restrict__ input,     // [512,64,512] fp32
    const float* __restrict__ c0,        // [64,512] fp32
    const unsigned short* __restrict__ WihF,
    const unsigned short* __restrict__ WhhF,
    const float* __restrict__ bias,
    unsigned short* __restrict__ hbuf,   // [2][BH] bf16
    int* __restrict__ hflag,             // [T_STEPS][NBLOCKS]
    float* __restrict__ out)             // [T*BH | BH | BH] fp32
{
    __shared__ unsigned short WhhL[WCHUNKS * 8];   // 64 KB, whole t-loop
    __shared__ f32x4 ring[RING][4][256];   // [slot][gate][bt*64+lane] = 48 KB
    __shared__ int xg_ready[RING][4];      // step+1 when slot/bt produced
    __shared__ int cons[4];                // xg consumed up to (step+1) per bt
    __shared__ int arr2[2];                // publish-barrier arrivals (ping-pong)
    __shared__ int mirror;                 // wave0's relay of global flag state

    const int tid  = threadIdx.x;
    const int lane = tid & 63;
    const int w    = tid >> 6;      // 0..7
    const int bt   = w & 3;         // batch tile
    const int jt   = blockIdx.x;    // j-tile 0..31
    const int quad = lane >> 4;
    const int lr   = lane & 15;

    if (tid < RING * 4)              (&xg_ready[0][0])[tid] = 0;
    else if (tid < RING * 4 + 4)     cons[tid - RING * 4] = 0;
    else if (tid < RING * 4 + 6)     arr2[tid - RING * 4 - 4] = 0;
    else if (tid == RING * 4 + 6)    mirror = 0;

    // cooperative stage: this block's W_hh fragment slice -> LDS (all 8 waves)
    {
        const short8* src = reinterpret_cast<const short8*>(
            WhhF + (size_t)jt * WCHUNKS * 8);
        short8* dst = reinterpret_cast<short8*>(WhhL);
        for (int idx = tid; idx < WCHUNKS; idx += 512) dst[idx] = src[idx];
    }
    __syncthreads();   // LDS staged + sync vars init, before role divergence

    const int brow  = bt * 16 + lr;           // batch row of this lane's cells
    const int jbase = jt * 16 + quad * 4;     // first of 4 consecutive j columns

    if (w >= 4) {
        // ---------------- x-producer wave (paired with rec wave bt) ----------------
        float bs[4][4];
#pragma unroll
        for (int g = 0; g < 4; ++g)
#pragma unroll
            for (int r = 0; r < 4; ++r)
                bs[g][r] = bias[g * HID + jbase + r];
        const unsigned short* wih_lane =
            WihF + (size_t)jt * WCHUNKS * 8 + (size_t)lane * 8;

        // reg-cache gates 0-1 of W_ih (loop-invariant; halves per-step L2 pull)
        short8 wih_reg[2][16];
#pragma unroll
        for (int g = 0; g < 2; ++g)
#pragma unroll
            for (int kb = 0; kb < 16; ++kb)
                wih_reg[g][kb] = *reinterpret_cast<const short8*>(
                    wih_lane + ((size_t)(g * 16 + kb) * 64) * 8);

        for (int t = 0; t < T_STEPS; ++t) {
            const int s = t % RING;
            if (t >= RING) {   // slot free once paired consumer read xg[t-RING]
                while (__hip_atomic_load(&cons[bt], __ATOMIC_ACQUIRE,
                                         __HIP_MEMORY_SCOPE_WORKGROUP) < t - (RING - 1))
                    __builtin_amdgcn_s_sleep(2);
            }
            f32x4 acc[4];
#pragma unroll
            for (int g = 0; g < 4; ++g)
                acc[g] = (f32x4){bs[g][0], bs[g][1], bs[g][2], bs[g][3]};
            const float* xp = input + ((size_t)t * BATCH + brow) * HID + quad * 8;
#pragma unroll
            for (int kb = 0; kb < 16; ++kb) {
                const f32x4 f0 = *reinterpret_cast<const f32x4*>(xp + kb * 32);
                const f32x4 f1 = *reinterpret_cast<const f32x4*>(xp + kb * 32 + 4);
                union { __hip_bfloat162 b2[4]; short8 s8; } bu;
                bu.b2[0] = __float22bfloat162_rn(make_float2(f0.x, f0.y));
                bu.b2[1] = __float22bfloat162_rn(make_float2(f0.z, f0.w));
                bu.b2[2] = __float22bfloat162_rn(make_float2(f1.x, f1.y));
                bu.b2[3] = __float22bfloat162_rn(make_float2(f1.z, f1.w));
#pragma unroll
                for (int g = 0; g < 2; ++g)
                    acc[g] = __builtin_amdgcn_mfma_f32_16x16x32_bf16(
                        wih_reg[g][kb], bu.s8, acc[g], 0, 0, 0);
#pragma unroll
                for (int g = 2; g < 4; ++g) {
                    short8 afrag = *reinterpret_cast<const short8*>(
                        wih_lane + ((size_t)(g * 16 + kb) * 64) * 8);
                    acc[g] = __builtin_amdgcn_mfma_f32_16x16x32_bf16(
                        afrag, bu.s8, acc[g], 0, 0, 0);
                }
            }
#pragma unroll
            for (int g = 0; g < 4; ++g)
                ring[s][g][bt * 64 + lane] = acc[g];     // ds_write_b128
            // release: drains lgkm before flag; consumer acquire pairs with it
            __hip_atomic_store(&xg_ready[s][bt], t + 1, __ATOMIC_RELEASE,
                               __HIP_MEMORY_SCOPE_WORKGROUP);
        }
        return;
    }

    // ---------------- recurrent wave ----------------
    __builtin_amdgcn_s_setprio(1);   // favor the critical-path waves

    f32x4 c = *reinterpret_cast<const f32x4*>(c0 + (size_t)brow * HID + jbase);
    float hlast[4];

    // reg-cache gates 0-1 of W_hh from LDS (loop-invariant, 64 VGPRs)
    short8 whh_reg[2][16];
#pragma unroll
    for (int g = 0; g < 2; ++g)
#pragma unroll
        for (int kb = 0; kb < 16; ++kb)
            whh_reg[g][kb] =
                reinterpret_cast<const short8*>(WhhL)[(g * 16 + kb) * 64 + lane];

    // prologue: xg for step 0
    f32x4 xg[4];
    {
        while (__hip_atomic_load(&xg_ready[0][bt], __ATOMIC_ACQUIRE,
                                 __HIP_MEMORY_SCOPE_WORKGROUP) < 1)
            __builtin_amdgcn_s_sleep(1);
#pragma unroll
        for (int g = 0; g < 4; ++g) xg[g] = ring[0][g][bt * 64 + lane];
        __hip_atomic_store(&cons[bt], 1, __ATOMIC_RELEASE,
                           __HIP_MEMORY_SCOPE_WORKGROUP);
    }

    for (int t = 0; t < T_STEPS; ++t) {
        // wait for h_t: wave0 polls the 32 per-block flags (agent scope), relays
        if (t > 0) {
            if (w == 0) {
                int* hf = hflag + (size_t)(t - 1) * NBLOCKS;
                for (;;) {
                    int f = (lane < NBLOCKS)
                        ? __hip_atomic_load(&hf[lane], __ATOMIC_RELAXED,
                                            __HIP_MEMORY_SCOPE_AGENT)
                        : 1;
                    if (__all(f != 0)) break;
                    __builtin_amdgcn_s_sleep(1);
                }
                __hip_atomic_store(&mirror, t, __ATOMIC_RELEASE,
                                   __HIP_MEMORY_SCOPE_WORKGROUP);
            } else {
                while (__hip_atomic_load(&mirror, __ATOMIC_ACQUIRE,
                                         __HIP_MEMORY_SCOPE_WORKGROUP) < t)
                    __builtin_amdgcn_s_sleep(1);
            }
            __atomic_signal_fence(__ATOMIC_ACQ_REL);   // no h-load hoist past poll
            __builtin_amdgcn_sched_barrier(0);
        }

        // batched h loads: 16 x dwordx4 (L1/L2-bypass), single drain
        const unsigned short* hp =
            hbuf + (size_t)(t & 1) * BH + (size_t)brow * HID + quad * 8;
        short8 hreg[16];
#pragma unroll
        for (int kb = 0; kb < 16; ++kb) hreg[kb] = sysload16(hp + kb * 32);
        asm volatile("s_waitcnt vmcnt(0)" ::: "memory");
        __builtin_amdgcn_sched_barrier(0);

        // h-side MFMA: gates 0-1 from registers, gates 2-3 from LDS
        f32x4 acc[4];
#pragma unroll
        for (int g = 0; g < 4; ++g) acc[g] = (f32x4){0.f, 0.f, 0.f, 0.f};
#pragma unroll
        for (int kb = 0; kb < 16; ++kb) {
#pragma unroll
            for (int g = 0; g < 2; ++g)
                acc[g] = __builtin_amdgcn_mfma_f32_16x16x32_bf16(
                    whh_reg[g][kb], hreg[kb], acc[g], 0, 0, 0);
#pragma unroll
            for (int g = 2; g < 4; ++g) {
                short8 afrag =
                    reinterpret_cast<const short8*>(WhhL)[(g * 16 + kb) * 64 + lane];
                acc[g] = __builtin_amdgcn_mfma_f32_16x16x32_bf16(
                    afrag, hreg[kb], acc[g], 0, 0, 0);
            }
        }

        // LSTM cell (xg already contains bias + x-projection)
        unsigned long long hpack = 0;
        f32x4 outv;
#pragma unroll
        for (int r = 0; r < 4; ++r) {
            const float i_ = sigmoidf_fast(acc[0][r] + xg[0][r]);
            const float f_ = sigmoidf_fast(acc[1][r] + xg[1][r]);
            const float g_ = tanhf_fast(acc[2][r] + xg[2][r]);
            const float o_ = sigmoidf_fast(acc[3][r] + xg[3][r]);
            const float cr = f_ * c[r] + i_ * g_;
            c[r] = cr;
            const float h = o_ * tanhf_fast(cr);
            hlast[r] = h;
            outv[r] = h;
            hpack |= (unsigned long long)f2bfu(h) << (16 * r);
        }

        // publish h_{t+1} (agent scope) -> drain (h store only) -> flag ASAP
        __hip_atomic_store(reinterpret_cast<unsigned long long*>(
                               hbuf + (size_t)((t + 1) & 1) * BH +
                               (size_t)brow * HID + jbase),
                           hpack, __ATOMIC_RELAXED, __HIP_MEMORY_SCOPE_AGENT);
        __threadfence_block();   // s_waitcnt vmcnt(0) lgkmcnt(0); no cache ops
        if (lane == 0) {
            int old = atomicAdd(&arr2[t & 1], 1);
            if (old == 3) {
                arr2[t & 1] = 0;
                __hip_atomic_store(&hflag[(size_t)t * NBLOCKS + jt], 1,
                                   __ATOMIC_RELAXED, __HIP_MEMORY_SCOPE_AGENT);
            }
        }

        // off critical path: out store, then next step's xg from the LDS ring
        __builtin_nontemporal_store(
            outv, reinterpret_cast<f32x4*>(
                      out + ((size_t)t * BATCH + brow) * HID + jbase));
        if (t + 1 < T_STEPS) {
            const int sn = (t + 1) % RING;
            while (__hip_atomic_load(&xg_ready[sn][bt], __ATOMIC_ACQUIRE,
                                     __HIP_MEMORY_SCOPE_WORKGROUP) < t + 2)
                __builtin_amdgcn_s_sleep(1);
#pragma unroll
            for (int g = 0; g < 4; ++g) xg[g] = ring[sn][g][bt * 64 + lane];
            __hip_atomic_store(&cons[bt], t + 2, __ATOMIC_RELEASE,
                               __HIP_MEMORY_SCOPE_WORKGROUP);
        }
    }

    // tails: hT, cT from registers
    float* hT = out + (size_t)T_STEPS * BH;
    float* cT = hT + BH;
    f32x4 hv4;
#pragma unroll
    for (int r = 0; r < 4; ++r) hv4[r] = hlast[r];
    *reinterpret_cast<f32x4*>(hT + (size_t)brow * HID + jbase) = hv4;
    *reinterpret_cast<f32x4*>(cT + (size_t)brow * HID + jbase) = c;
}

extern "C" void kernel_launch(void* const* d_in, const int* in_sizes, int n_in,
                              void* d_out, int out_size, void* d_ws, size_t ws_size,
                              hipStream_t stream) {
    const float* input = (const float*)d_in[0];
    const float* h0    = (const float*)d_in[1];
    const float* c0    = (const float*)d_in[2];
    const float* W_ih  = (const float*)d_in[3];
    const float* W_hh  = (const float*)d_in[4];
    const float* b_ih  = (const float*)d_in[5];
    const float* b_hh  = (const float*)d_in[6];
    float* out = (float*)d_out;

    // ws layout (~4.5 MB): WihF | WhhF (bf16 frags, 2 MB each) | hbuf[2] bf16 |
    //                      bias fp32 | hflag int[512*32]
    char* ws = (char*)d_ws;
    unsigned short* WihF = (unsigned short*)ws;
    unsigned short* WhhF = WihF + (size_t)GATES * HID;
    unsigned short* hbuf = WhhF + (size_t)GATES * HID;
    float* bias = (float*)(hbuf + 2 * BH);
    int* hflag = (int*)(bias + GATES);

    prep<<<1024, 256, 0, stream>>>(h0, W_ih, W_hh, b_ih, b_hh,
                                   WihF, WhhF, hbuf, bias, hflag);

    lstm_persistent<<<NBLOCKS, 512, 0, stream>>>(
        input, c0, WihF, WhhF, bias, hbuf, hflag, out);
}